// Round 15
// baseline (171.303 us; speedup 1.0000x reference)
//
#include <hip/hip_runtime.h>
#include <stdint.h>

#define S_LEN 2048
#define DMODEL 1024
#define NBATCH 4
#define MROWS (NBATCH * S_LEN)  // 8192

typedef __bf16 bf16x8 __attribute__((ext_vector_type(8)));
typedef float f32x4 __attribute__((ext_vector_type(4)));

__device__ __forceinline__ unsigned short f2bf(float f) {
  unsigned int x = __builtin_bit_cast(unsigned int, f);
  x += 0x7FFFu + ((x >> 16) & 1u);
  return (unsigned short)(x >> 16);
}

template <int N>
__device__ __forceinline__ void waitvm() {
  static_assert(N <= 8, "vmcnt range");
  if constexpr (N < 0) {}
  else if constexpr (N == 0) asm volatile("s_waitcnt vmcnt(0)" ::: "memory");
  else if constexpr (N == 1) asm volatile("s_waitcnt vmcnt(1)" ::: "memory");
  else if constexpr (N == 2) asm volatile("s_waitcnt vmcnt(2)" ::: "memory");
  else if constexpr (N == 3) asm volatile("s_waitcnt vmcnt(3)" ::: "memory");
  else if constexpr (N == 4) asm volatile("s_waitcnt vmcnt(4)" ::: "memory");
  else if constexpr (N == 5) asm volatile("s_waitcnt vmcnt(5)" ::: "memory");
  else if constexpr (N == 6) asm volatile("s_waitcnt vmcnt(6)" ::: "memory");
  else if constexpr (N == 7) asm volatile("s_waitcnt vmcnt(7)" ::: "memory");
  else asm volatile("s_waitcnt vmcnt(8)" ::: "memory");
}
#define BARRIER() do { __builtin_amdgcn_s_barrier(); asm volatile("" ::: "memory"); } while (0)
#define LGKM0() do { asm volatile("s_waitcnt lgkmcnt(0)" ::: "memory"); \
                     __builtin_amdgcn_sched_barrier(0); } while (0)

// ---------------- fused input/weight/bias prep (single launch) ----------------
__global__ void prep_all_kernel(const float* __restrict__ x, const float* __restrict__ Wq,
                                const float* __restrict__ Wk, const float* __restrict__ Wv,
                                const float* __restrict__ bq, const float* __restrict__ bk,
                                ushort4* __restrict__ xb, ushort4* __restrict__ Wqkb,
                                ushort4* __restrict__ Wvb, float4* __restrict__ bqk) {
  const int NX = MROWS * DMODEL / 4;   // 2,097,152
  const int NW = DMODEL * DMODEL / 4;  // 262,144
  int i = blockIdx.x * blockDim.x + threadIdx.x;
  float4 v;
  if (i < NX) {
    v = reinterpret_cast<const float4*>(x)[i];
    ushort4 o; o.x = f2bf(v.x); o.y = f2bf(v.y); o.z = f2bf(v.z); o.w = f2bf(v.w);
    xb[i] = o;
  } else {
    int j = i - NX;
    if (j < NW) v = reinterpret_cast<const float4*>(Wq)[j];
    else if (j < 2 * NW) v = reinterpret_cast<const float4*>(Wk)[j - NW];
    else v = reinterpret_cast<const float4*>(Wv)[j - 2 * NW];
    ushort4 o; o.x = f2bf(v.x); o.y = f2bf(v.y); o.z = f2bf(v.z); o.w = f2bf(v.w);
    if (j < 2 * NW) Wqkb[j] = o;
    else Wvb[j - 2 * NW] = o;
    if (j < 512) bqk[j] = (j < 256) ? reinterpret_cast<const float4*>(bq)[j]
                                    : reinterpret_cast<const float4*>(bk)[j - 256];
  }
}

// ---------------- 16-wave 3-phase GEMM (256x256 tile): C = A * B^T ----------------
// ROUND-15: five intra-block schedule changes were all neutral -> the wall is
// wave-level parallelism: 512thr/128KB-LDS = 1 block/CU = 2 waves/SIMD, all
// barrier-locked, so every load-return gap is exposed. This variant runs
// 1024 threads = 16 waves (4M x 4N, per-wave 64x64 output) -> 4 waves/SIMD
// from one block; independent waves overlap MFMA/VMEM/drains (m114).
// Register budget (unified VGPR+AGPR, must fit 128/wave for 4/SIMD):
// acc 4x4xf32x4 = 64 + av 16 + bv0/bv1 32 + addressing ~12 ~= 124.
// Same proven r14 machinery: 3-phase full-K walk, kk-outer MFMA clusters,
// XOR swizzle (16B-slot ^= row&7) via pre-swizzled global source, LGKM0.
// Staging: 1 global_load_lds per wave per half (16 waves x 1KB = 16KB half).
// Stage slots (t stages t+1): P_a: A0'+B0' (2 loads), P_b: B1' (1), P_c: A1' (1).
// Guards (r7 rule; per-wave in-flight traced): prologue vm<2>;
// P_a vm<3> (B1), P_b vm<3> (A1), P_c vm<2> (A0',B0'); drain vm<1>, vm<0>.
// All LDS regions keep 3-barrier read->overwrite distance (buf vs nb).
// EP: 0 = bf16 out + bias[col]; 1 = f32 out * scale.
template <int EP, int NT>
__global__ __launch_bounds__(1024, 1) void gemm16(
    const unsigned short* __restrict__ A, const unsigned short* __restrict__ Bm,
    void* __restrict__ Cp, const float* __restrict__ bias,
    int lda, int ldb, int ldc, float scale,
    long zsA, long zsB, long zsC) {
  constexpr int BK = 64;                // elements (128 bytes)
  constexpr int ATILE = 256 * 128;      // 32KB
  constexpr int TILE2 = ATILE * 2;      // A+B per buffer = 64KB
  constexpr int HALF = 128 * 128;       // 16KB (128 rows)

  __shared__ alignas(16) char lds[TILE2 * 2];  // 128KB

  const int tid = threadIdx.x;
  const int l = tid & 63;
  const int w = tid >> 6;   // 0..15
  const int wm = w >> 2;    // 0..3
  const int wn = w & 3;     // 0..3

  // bijective XCD-chunked swizzle (nwg % 8 == 0 for all our grids)
  const int gx = gridDim.x;
  const int nwg = gridDim.x * gridDim.y;
  int n = blockIdx.y * gx + blockIdx.x;
  int n2 = (n & 7) * (nwg >> 3) + (n >> 3);
  const int tileM = (n2 / gx) * 256;
  const int tileN = (n2 % gx) * 256;

  const int z = blockIdx.z;
  const unsigned short* Ab = A + (size_t)z * zsA;
  const unsigned short* Bb = Bm + (size_t)z * zsB;

  const int srow = l >> 3;
  const int scol = (((l & 7) ^ srow) * 16);

  auto stageA = [&](int buf, int t, int h) {
    int row = h * 128 + w * 8 + srow;
    const char* g = (const char*)(Ab + (size_t)(tileM + row) * lda + t * BK) + scol;
    char* d = lds + buf * TILE2 + h * HALF + w * 1024;
    __builtin_amdgcn_global_load_lds(
        (const __attribute__((address_space(1))) void*)g,
        (__attribute__((address_space(3))) void*)d, 16, 0, 0);
  };
  auto stageB = [&](int buf, int t, int h) {
    int row = h * 128 + w * 8 + srow;
    const char* g = (const char*)(Bb + (size_t)(tileN + row) * ldb + t * BK) + scol;
    char* d = lds + buf * TILE2 + ATILE + h * HALF + w * 1024;
    __builtin_amdgcn_global_load_lds(
        (const __attribute__((address_space(1))) void*)g,
        (__attribute__((address_space(3))) void*)d, 16, 0, 0);
  };

  f32x4 acc[4][4];
#pragma unroll
  for (int m = 0; m < 4; ++m)
#pragma unroll
    for (int nn = 0; nn < 4; ++nn) acc[m][nn] = f32x4{0.f, 0.f, 0.f, 0.f};

  const int frow = l & 15;
  auto rdA = [&](int buf, int mh, int m, int kk) -> bf16x8 {
    int row = mh * 128 + wm * 32 + m * 16 + frow;
    int col = (kk * 64 + ((l >> 4) * 16)) ^ ((row & 7) << 4);
    return *reinterpret_cast<const bf16x8*>(lds + buf * TILE2 + row * 128 + col);
  };
  auto rdB = [&](int buf, int nh, int nn, int kk) -> bf16x8 {
    int row = nh * 128 + wn * 32 + nn * 16 + frow;
    int col = (kk * 64 + ((l >> 4) * 16)) ^ ((row & 7) << 4);
    return *reinterpret_cast<const bf16x8*>(lds + buf * TILE2 + ATILE + row * 128 + col);
  };

  bf16x8 avF[2][2];             // rotating A half set [m][kk]
  bf16x8 bv0[2][2], bv1[2][2];  // B halves held per tile [nn][kk]

  auto rdAfull = [&](int buf, int mh) {
#pragma unroll
    for (int m = 0; m < 2; ++m)
#pragma unroll
      for (int kk = 0; kk < 2; ++kk) avF[m][kk] = rdA(buf, mh, m, kk);
  };
  auto rdBfull = [&](int buf, int nh, bf16x8 (&bv)[2][2]) {
#pragma unroll
    for (int nn = 0; nn < 2; ++nn)
#pragma unroll
      for (int kk = 0; kk < 2; ++kk) bv[nn][kk] = rdB(buf, nh, nn, kk);
  };
  // kk OUTER: 4 independent accumulators per kk-step
  auto mfc = [&](int mh, bf16x8 (&bv)[2][2], int nh) {
    __builtin_amdgcn_s_setprio(1);
#pragma unroll
    for (int kk = 0; kk < 2; ++kk)
#pragma unroll
      for (int m = 0; m < 2; ++m)
#pragma unroll
        for (int nn = 0; nn < 2; ++nn)
          acc[mh * 2 + m][nh * 2 + nn] = __builtin_amdgcn_mfma_f32_16x16x32_bf16(
              avF[m][kk], bv[nn][kk], acc[mh * 2 + m][nh * 2 + nn], 0, 0, 0);
    __builtin_amdgcn_s_setprio(0);
  };
  auto mfc2 = [&](int mh) {  // (A1,B1)+(A1,B0) merged, kk-outer
    __builtin_amdgcn_s_setprio(1);
#pragma unroll
    for (int kk = 0; kk < 2; ++kk)
#pragma unroll
      for (int m = 0; m < 2; ++m) {
#pragma unroll
        for (int nn = 0; nn < 2; ++nn)
          acc[mh * 2 + m][2 + nn] = __builtin_amdgcn_mfma_f32_16x16x32_bf16(
              avF[m][kk], bv1[nn][kk], acc[mh * 2 + m][2 + nn], 0, 0, 0);
#pragma unroll
        for (int nn = 0; nn < 2; ++nn)
          acc[mh * 2 + m][nn] = __builtin_amdgcn_mfma_f32_16x16x32_bf16(
              avF[m][kk], bv0[nn][kk], acc[mh * 2 + m][nn], 0, 0, 0);
      }
    __builtin_amdgcn_s_setprio(0);
  };

  // prologue: stage tile 0 (A0,B0,B1,A1 = 4 loads/wave); guard A0,B0
  stageA(0, 0, 0);
  stageB(0, 0, 0);
  stageB(0, 0, 1);
  stageA(0, 0, 1);
  waitvm<2>();
  BARRIER();

#pragma unroll 2
  for (int t = 0; t < NT - 1; ++t) {
    const int buf = t & 1, nb = buf ^ 1;
    // P_a: (A0,B0) full-K; stage A0'+B0'; guard B1(t) for P_b
    rdAfull(buf, 0); rdBfull(buf, 0, bv0);
    stageA(nb, t + 1, 0); stageB(nb, t + 1, 0);
    waitvm<3>(); BARRIER(); LGKM0();
    mfc(0, bv0, 0);
    // P_b: (A0,B1); stage B1'; guard A1(t) for P_c
    rdBfull(buf, 1, bv1);
    stageB(nb, t + 1, 1);
    waitvm<3>(); BARRIER(); LGKM0();
    mfc(0, bv1, 1);
    // P_c: (A1,B1)+(A1,B0); stage A1'; guard A0',B0' for t+1 P_a
    rdAfull(buf, 1);
    stageA(nb, t + 1, 1);
    waitvm<2>(); BARRIER(); LGKM0();
    mfc2(1);
  }
  {  // peeled last tile
    const int buf = (NT - 1) & 1;
    rdAfull(buf, 0); rdBfull(buf, 0, bv0);
    waitvm<1>(); BARRIER(); LGKM0();
    mfc(0, bv0, 0);
    rdBfull(buf, 1, bv1);
    waitvm<0>(); BARRIER(); LGKM0();
    mfc(0, bv1, 1);
    rdAfull(buf, 1);
    LGKM0();
    mfc2(1);
  }

  // epilogue: C/D layout (m89): col = lane&15, row = (lane>>4)*4 + j
  const int lr = (l >> 4) * 4;
  const int lc = l & 15;
#pragma unroll
  for (int mh = 0; mh < 2; ++mh) {
#pragma unroll
    for (int m = 0; m < 2; ++m) {
#pragma unroll
      for (int nh = 0; nh < 2; ++nh) {
#pragma unroll
        for (int nn = 0; nn < 2; ++nn) {
          int gr = tileM + mh * 128 + wm * 32 + m * 16 + lr;
          int gc = tileN + nh * 128 + wn * 32 + nn * 16 + lc;
          f32x4 v = acc[mh * 2 + m][nh * 2 + nn];
          if constexpr (EP == 0) {
            unsigned short* C = (unsigned short*)Cp + (size_t)z * zsC;
            float bb = bias[gc];
#pragma unroll
            for (int j = 0; j < 4; ++j) C[(size_t)(gr + j) * ldc + gc] = f2bf(v[j] + bb);
          } else {
            float* C = (float*)Cp + (size_t)z * zsC;
#pragma unroll
            for (int j = 0; j < 4; ++j) C[(size_t)(gr + j) * ldc + gc] = v[j] * scale;
          }
        }
      }
    }
  }
}

// ---------------- 8-wave 3-phase GEMM (r14, proven; used for Vt and PV) ----------------
template <int BM_, int EP, int NT>
__global__ __launch_bounds__(512, 2) void gemm8(
    const unsigned short* __restrict__ A, const unsigned short* __restrict__ Bm,
    void* __restrict__ Cp, const float* __restrict__ bias,
    int lda, int ldb, int ldc, float scale,
    long zsA, long zsB, long zsC) {
  constexpr int BN_ = 256;
  constexpr int BK = 64;
  constexpr int RA = BM_ / 128;
  constexpr int HALF_A = (BM_ / 2) * 128;
  constexpr int HALF_B = 128 * 128;
  constexpr int ATILE = BM_ * 128;
  constexpr int BTILE = BN_ * 128;
  constexpr int MREP = BM_ / 32;
  constexpr int MQ = MREP / 2;
  constexpr int VPRO = (BM_ == 256) ? 4 : 3;
  constexpr int W_PA = (BM_ == 256) ? 6 : 4;
  constexpr int W_PB = (BM_ == 256) ? 6 : 5;
  constexpr int W_PC = (BM_ == 256) ? 4 : 3;
  constexpr int VDA  = (BM_ == 256) ? 2 : 1;

  __shared__ alignas(16) char lds[(ATILE + BTILE) * 2];

  const int tid = threadIdx.x;
  const int l = tid & 63;
  const int w = tid >> 6;
  const int wm = w >> 2;
  const int wn = w & 3;

  const int gx = gridDim.x;
  const int nwg = gridDim.x * gridDim.y;
  int n = blockIdx.y * gx + blockIdx.x;
  int n2 = (n & 7) * (nwg >> 3) + (n >> 3);
  const int tileM = (n2 / gx) * BM_;
  const int tileN = (n2 % gx) * BN_;

  const int z = blockIdx.z;
  const unsigned short* Ab = A + (size_t)z * zsA;
  const unsigned short* Bb = Bm + (size_t)z * zsB;

  const int srow = l >> 3;
  const int scol = (((l & 7) ^ srow) * 16);

  auto stageA = [&](int buf, int t, int h) {
#pragma unroll
    for (int r = 0; r < RA; ++r) {
      int row = h * (BM_ / 2) + r * 64 + w * 8 + srow;
      const char* g = (const char*)(Ab + (size_t)(tileM + row) * lda + t * BK) + scol;
      char* d = lds + buf * (ATILE + BTILE) + h * HALF_A + r * 8192 + w * 1024;
      __builtin_amdgcn_global_load_lds(
          (const __attribute__((address_space(1))) void*)g,
          (__attribute__((address_space(3))) void*)d, 16, 0, 0);
    }
  };
  auto stageB = [&](int buf, int t, int h) {
#pragma unroll
    for (int r = 0; r < 2; ++r) {
      int row = h * 128 + r * 64 + w * 8 + srow;
      const char* g = (const char*)(Bb + (size_t)(tileN + row) * ldb + t * BK) + scol;
      char* d = lds + buf * (ATILE + BTILE) + ATILE + h * HALF_B + r * 8192 + w * 1024;
      __builtin_amdgcn_global_load_lds(
          (const __attribute__((address_space(1))) void*)g,
          (__attribute__((address_space(3))) void*)d, 16, 0, 0);
    }
  };

  f32x4 acc[MREP][4];
#pragma unroll
  for (int m = 0; m < MREP; ++m)
#pragma unroll
    for (int nn = 0; nn < 4; ++nn) acc[m][nn] = f32x4{0.f, 0.f, 0.f, 0.f};

  const int frow = l & 15;
  auto rdA = [&](int buf, int mh, int m, int kk) -> bf16x8 {
    int row = mh * (BM_ / 2) + wm * (BM_ / 4) + m * 16 + frow;
    int col = (kk * 64 + ((l >> 4) * 16)) ^ ((row & 7) << 4);
    return *reinterpret_cast<const bf16x8*>(lds + buf * (ATILE + BTILE) + row * 128 + col);
  };
  auto rdB = [&](int buf, int nh, int nn, int kk) -> bf16x8 {
    int row = nh * 128 + wn * 32 + nn * 16 + frow;
    int col = (kk * 64 + ((l >> 4) * 16)) ^ ((row & 7) << 4);
    return *reinterpret_cast<const bf16x8*>(lds + buf * (ATILE + BTILE) + ATILE + row * 128 + col);
  };

  bf16x8 avF[MQ][2];
  bf16x8 bv0[2][2], bv1[2][2];

  auto rdAfull = [&](int buf, int mh) {
#pragma unroll
    for (int m = 0; m < MQ; ++m)
#pragma unroll
      for (int kk = 0; kk < 2; ++kk) avF[m][kk] = rdA(buf, mh, m, kk);
  };
  auto rdBfull = [&](int buf, int nh, bf16x8 (&bv)[2][2]) {
#pragma unroll
    for (int nn = 0; nn < 2; ++nn)
#pragma unroll
      for (int kk = 0; kk < 2; ++kk) bv[nn][kk] = rdB(buf, nh, nn, kk);
  };
  auto mfc = [&](int mh, bf16x8 (&bv)[2][2], int nh) {
    __builtin_amdgcn_s_setprio(1);
#pragma unroll
    for (int kk = 0; kk < 2; ++kk)
#pragma unroll
      for (int m = 0; m < MQ; ++m)
#pragma unroll
        for (int nn = 0; nn < 2; ++nn)
          acc[mh * MQ + m][nh * 2 + nn] = __builtin_amdgcn_mfma_f32_16x16x32_bf16(
              avF[m][kk], bv[nn][kk], acc[mh * MQ + m][nh * 2 + nn], 0, 0, 0);
    __builtin_amdgcn_s_setprio(0);
  };
  auto mfc2 = [&](int mh) {
    __builtin_amdgcn_s_setprio(1);
#pragma unroll
    for (int kk = 0; kk < 2; ++kk)
#pragma unroll
      for (int m = 0; m < MQ; ++m) {
#pragma unroll
        for (int nn = 0; nn < 2; ++nn)
          acc[mh * MQ + m][2 + nn] = __builtin_amdgcn_mfma_f32_16x16x32_bf16(
              avF[m][kk], bv1[nn][kk], acc[mh * MQ + m][2 + nn], 0, 0, 0);
#pragma unroll
        for (int nn = 0; nn < 2; ++nn)
          acc[mh * MQ + m][nn] = __builtin_amdgcn_mfma_f32_16x16x32_bf16(
              avF[m][kk], bv0[nn][kk], acc[mh * MQ + m][nn], 0, 0, 0);
      }
    __builtin_amdgcn_s_setprio(0);
  };

  stageA(0, 0, 0);
  stageB(0, 0, 0);
  stageB(0, 0, 1);
  stageA(0, 0, 1);
  waitvm<VPRO>();
  BARRIER();

#pragma unroll 2
  for (int t = 0; t < NT - 1; ++t) {
    const int buf = t & 1, nb = buf ^ 1;
    rdAfull(buf, 0); rdBfull(buf, 0, bv0);
    stageA(nb, t + 1, 0); stageB(nb, t + 1, 0);
    waitvm<W_PA>(); BARRIER(); LGKM0();
    mfc(0, bv0, 0);
    rdBfull(buf, 1, bv1);
    stageB(nb, t + 1, 1);
    waitvm<W_PB>(); BARRIER(); LGKM0();
    mfc(0, bv1, 1);
    rdAfull(buf, 1);
    stageA(nb, t + 1, 1);
    waitvm<W_PC>(); BARRIER(); LGKM0();
    mfc2(1);
  }
  {
    const int buf = (NT - 1) & 1;
    rdAfull(buf, 0); rdBfull(buf, 0, bv0);
    waitvm<VDA>(); BARRIER(); LGKM0();
    mfc(0, bv0, 0);
    rdBfull(buf, 1, bv1);
    waitvm<0>(); BARRIER(); LGKM0();
    mfc(0, bv1, 1);
    rdAfull(buf, 1);
    LGKM0();
    mfc2(1);
  }

  const int lr = (l >> 4) * 4;
  const int lc = l & 15;
#pragma unroll
  for (int mh = 0; mh < 2; ++mh) {
#pragma unroll
    for (int m = 0; m < MQ; ++m) {
#pragma unroll
      for (int nh = 0; nh < 2; ++nh) {
#pragma unroll
        for (int nn = 0; nn < 2; ++nn) {
          int gr = tileM + mh * (BM_ / 2) + wm * (BM_ / 4) + m * 16 + lr;
          int gc = tileN + nh * 128 + wn * 32 + nn * 16 + lc;
          f32x4 v = acc[mh * MQ + m][nh * 2 + nn];
          if constexpr (EP == 0 || EP == 3) {
            unsigned short* C = (unsigned short*)Cp + (size_t)z * zsC;
#pragma unroll
            for (int j = 0; j < 4; ++j) {
              float bb = (EP == 0) ? bias[gc] : bias[gr + j];
              C[(size_t)(gr + j) * ldc + gc] = f2bf(v[j] + bb);
            }
          } else {
            float* C = (float*)Cp + (size_t)z * zsC;
#pragma unroll
            for (int j = 0; j < 4; ++j)
              C[(size_t)(gr + j) * ldc + gc] = (EP == 1) ? v[j] * scale : v[j];
          }
        }
      }
    }
  }
}

// ---------------- row softmax: fp32 [8192 x 2048] -> bf16 P ----------------
__global__ __launch_bounds__(256) void softmax_kernel(const float* __restrict__ Sb,
                                                      unsigned short* __restrict__ P) {
  const size_t row = blockIdx.x;
  const float* sp = Sb + row * S_LEN;
  const int t = threadIdx.x;
  const int wid = t >> 6, lane = t & 63;
  float4 v0 = reinterpret_cast<const float4*>(sp)[t * 2];
  float4 v1 = reinterpret_cast<const float4*>(sp)[t * 2 + 1];
  float s[8] = {v0.x, v0.y, v0.z, v0.w, v1.x, v1.y, v1.z, v1.w};
  float mx = s[0];
#pragma unroll
  for (int i = 1; i < 8; ++i) mx = fmaxf(mx, s[i]);
#pragma unroll
  for (int o = 32; o > 0; o >>= 1) mx = fmaxf(mx, __shfl_xor(mx, o));
  __shared__ float redm[4];
  __shared__ float reds[4];
  if (lane == 0) redm[wid] = mx;
  __syncthreads();
  mx = fmaxf(fmaxf(redm[0], redm[1]), fmaxf(redm[2], redm[3]));
  float e[8];
  float sum = 0.f;
#pragma unroll
  for (int i = 0; i < 8; ++i) { e[i] = __expf(s[i] - mx); sum += e[i]; }
#pragma unroll
  for (int o = 32; o > 0; o >>= 1) sum += __shfl_xor(sum, o);
  if (lane == 0) reds[wid] = sum;
  __syncthreads();
  sum = reds[0] + reds[1] + reds[2] + reds[3];
  float inv = 1.0f / sum;
  ushort4 o0, o1;
  o0.x = f2bf(e[0] * inv); o0.y = f2bf(e[1] * inv); o0.z = f2bf(e[2] * inv); o0.w = f2bf(e[3] * inv);
  o1.x = f2bf(e[4] * inv); o1.y = f2bf(e[5] * inv); o1.z = f2bf(e[6] * inv); o1.w = f2bf(e[7] * inv);
  ushort4* dp = reinterpret_cast<ushort4*>(P + row * S_LEN);
  dp[t * 2] = o0;
  dp[t * 2 + 1] = o1;
}

extern "C" void kernel_launch(void* const* d_in, const int* in_sizes, int n_in,
                              void* d_out, int out_size, void* d_ws, size_t ws_size,
                              hipStream_t stream) {
  (void)in_sizes; (void)n_in; (void)out_size;
  const float* x = (const float*)d_in[0];
  const float* Wq = (const float*)d_in[1];
  const float* bq = (const float*)d_in[2];
  const float* Wk = (const float*)d_in[3];
  const float* bk = (const float*)d_in[4];
  const float* Wv = (const float*)d_in[5];
  const float* bv = (const float*)d_in[6];
  float* out = (float*)d_out;

  // workspace layout (bytes), total ~135 MB:
  //   xb   bf16 [8192][1024]    @ 0       (16 MB)
  //   Wqkb bf16 [2048][1024]    @ 16 MB   (4 MB)   -- [Wq;Wk]
  //   Wvb  bf16 [1024][1024]    @ 20 MB   (2 MB)
  //   bqk  f32  [2048]          @ 22 MB   (8 KB)
  //   QKb  bf16 [8192][2048]    @ 23 MB   (32 MB)  -- reused as P after scores
  //   Sb   f32  [4][2048][2048] @ 55 MB   (64 MB)
  //   Vt   bf16 [4][1024][2048] @ 119 MB  (16 MB)
  if (ws_size < 141557760ull) return;
  char* ws = (char*)d_ws;
  unsigned short* xb   = (unsigned short*)(ws);
  unsigned short* Wqkb = (unsigned short*)(ws + 16777216);
  unsigned short* Wvb  = (unsigned short*)(ws + 20971520);
  float*          bqk  = (float*)(ws + 23068672);
  unsigned short* QKb  = (unsigned short*)(ws + 24117248);
  float*          Sb   = (float*)(ws + 57671680);
  unsigned short* Vt   = (unsigned short*)(ws + 124780544);
  unsigned short* P    = QKb;  // alias: QKb dead after scores GEMM

  // 1) fused input+weight+bias prep (single launch)
  const int NX = MROWS * DMODEL / 4, NW = DMODEL * DMODEL / 4;
  prep_all_kernel<<<dim3((NX + 3 * NW) / 256), 256, 0, stream>>>(
      x, Wq, Wk, Wv, bq, bk, (ushort4*)xb, (ushort4*)Wqkb, (ushort4*)Wvb, (float4*)bqk);

  // 2) QK projection (16-wave): [8192x2048] = x * [Wq;Wk]^T + bqk (grid 256)
  gemm16<0, 16><<<dim3(8, 32, 1), 1024, 0, stream>>>(
      xb, Wqkb, QKb, bqk, 1024, 1024, 2048, 1.f, 0, 0, 0);

  // 3) Vt = Wv * x^T + bv (per batch): grid (8,8,4) = 256 (8-wave, BM=128)
  gemm8<128, 3, 16><<<dim3(8, 8, 4), 512, 0, stream>>>(
      Wvb, xb, Vt, bv, 1024, 1024, 2048, 1.f,
      0, (long)S_LEN * DMODEL, (long)DMODEL * S_LEN);

  // 4) scores (16-wave): Sb = Q * K^T * 0.125 (per batch M=N=2048, K=1024)
  gemm16<1, 16><<<dim3(8, 8, 4), 1024, 0, stream>>>(
      QKb, QKb + 1024, Sb, nullptr, 2048, 2048, 2048, 0.125f,
      (long)S_LEN * 2048, (long)S_LEN * 2048, (long)S_LEN * S_LEN);

  // 5) row softmax -> bf16 P (aliases QKb)
  softmax_kernel<<<dim3(MROWS), 256, 0, stream>>>(Sb, P);

  // 6) out = P * Vt^T (per batch M=2048, N=1024, K=2048; grid 256, 8-wave)
  gemm8<128, 2, 32><<<dim3(4, 16, 4), 512, 0, stream>>>(
      P, Vt, out, nullptr, 2048, 2048, 1024, 1.f,
      (long)S_LEN * S_LEN, (long)DMODEL * S_LEN, (long)S_LEN * DMODEL);
}

// Round 16
// 169.177 us; speedup vs baseline: 1.0126x; 1.0126x over previous
//
#include <hip/hip_runtime.h>
#include <stdint.h>

#define S_LEN 2048
#define DMODEL 1024
#define NBATCH 4
#define MROWS (NBATCH * S_LEN)  // 8192

typedef __bf16 bf16x8 __attribute__((ext_vector_type(8)));
typedef float f32x4 __attribute__((ext_vector_type(4)));

__device__ __forceinline__ unsigned short f2bf(float f) {
  unsigned int x = __builtin_bit_cast(unsigned int, f);
  x += 0x7FFFu + ((x >> 16) & 1u);
  return (unsigned short)(x >> 16);
}

template <int N>
__device__ __forceinline__ void waitvm() {
  static_assert(N <= 8, "vmcnt range");
  if constexpr (N < 0) {}
  else if constexpr (N == 0) asm volatile("s_waitcnt vmcnt(0)" ::: "memory");
  else if constexpr (N == 1) asm volatile("s_waitcnt vmcnt(1)" ::: "memory");
  else if constexpr (N == 2) asm volatile("s_waitcnt vmcnt(2)" ::: "memory");
  else if constexpr (N == 3) asm volatile("s_waitcnt vmcnt(3)" ::: "memory");
  else if constexpr (N == 4) asm volatile("s_waitcnt vmcnt(4)" ::: "memory");
  else if constexpr (N == 5) asm volatile("s_waitcnt vmcnt(5)" ::: "memory");
  else if constexpr (N == 6) asm volatile("s_waitcnt vmcnt(6)" ::: "memory");
  else if constexpr (N == 7) asm volatile("s_waitcnt vmcnt(7)" ::: "memory");
  else asm volatile("s_waitcnt vmcnt(8)" ::: "memory");
}
#define BARRIER() do { __builtin_amdgcn_s_barrier(); asm volatile("" ::: "memory"); } while (0)
// Drain own LDS reads (WAR safety before boundary barrier). NO sched_barrier:
// r15 post-mortem -- sched_barrier(0) pinned reads/MFMA into serial blocks.
#define LGKM0() asm volatile("s_waitcnt lgkmcnt(0)" ::: "memory")

// ---------------- fused input/weight/bias prep (single launch) ----------------
__global__ void prep_all_kernel(const float* __restrict__ x, const float* __restrict__ Wq,
                                const float* __restrict__ Wk, const float* __restrict__ Wv,
                                const float* __restrict__ bq, const float* __restrict__ bk,
                                ushort4* __restrict__ xb, ushort4* __restrict__ Wqkb,
                                ushort4* __restrict__ Wvb, float4* __restrict__ bqk) {
  const int NX = MROWS * DMODEL / 4;   // 2,097,152
  const int NW = DMODEL * DMODEL / 4;  // 262,144
  int i = blockIdx.x * blockDim.x + threadIdx.x;
  float4 v;
  if (i < NX) {
    v = reinterpret_cast<const float4*>(x)[i];
    ushort4 o; o.x = f2bf(v.x); o.y = f2bf(v.y); o.z = f2bf(v.z); o.w = f2bf(v.w);
    xb[i] = o;
  } else {
    int j = i - NX;
    if (j < NW) v = reinterpret_cast<const float4*>(Wq)[j];
    else if (j < 2 * NW) v = reinterpret_cast<const float4*>(Wk)[j - NW];
    else v = reinterpret_cast<const float4*>(Wv)[j - 2 * NW];
    ushort4 o; o.x = f2bf(v.x); o.y = f2bf(v.y); o.z = f2bf(v.z); o.w = f2bf(v.w);
    if (j < 2 * NW) Wqkb[j] = o;
    else Wvb[j - 2 * NW] = o;
    if (j < 512) bqk[j] = (j < 256) ? reinterpret_cast<const float4*>(bq)[j]
                                    : reinterpret_cast<const float4*>(bk)[j - 256];
  }
}

// ---------------- tile-granular GEMM: C = A * B^T ----------------
// ROUND-16: bulk-synchronous -> tile-granular sync. r15 showed doubling
// occupancy LOWERS throughput -> the limiter is the per-phase stall quanta
// (3 vmcnt + 3 barriers + 3 lgkm/sched fences per tile), and sched_barrier(0)
// forbade ds_read/MFMA overlap. NEW: ONE barrier + ONE vmcnt(0) + ONE lgkm0
// per K-tile, at the tile boundary. No intra-tile sync at all -- the compiler
// software-pipelines the tile body (its per-fragment lgkmcnt(N) interleave is
// near-optimal), and waves drift within a tile, overlapping MFMA/LDS/VMEM
// across waves (m114) without barrier lockstep.
// Correctness:
//   RAW: boundary vmcnt(0)+BARRIER => tile t+1 fully LDS-resident before any
//        t+1 read. The 6-8 loads were issued a full tile (~4-6k cy) earlier,
//        so the vmcnt(0) is nearly free.
//   WAR: stages during tile t write buffer((t+1)&1) = tile t-1's buffer; every
//        wave drained its own t-1 ds_reads (LGKM0) before the boundary barrier
//        separating t-1 from t.
// Machinery unchanged from r14 (verified): XOR swizzle (16B-slot ^= row&7) via
// pre-swizzled global source + same on ds_read; kk-outer MFMA clusters;
// 16x16x32 core; 8 waves 2Mx4N; full-K quadrant register plan (avF/bv0/bv1).
// EP: 0 = bf16 out + bias[col]; 1 = f32 out * scale; 2 = f32 out;
//     3 = bf16 out + bias[ROW]  (Vt = Wv * x^T + bv)
template <int BM_, int EP, int NT>
__global__ __launch_bounds__(512, 2) void gemm8(
    const unsigned short* __restrict__ A, const unsigned short* __restrict__ Bm,
    void* __restrict__ Cp, const float* __restrict__ bias,
    int lda, int ldb, int ldc, float scale,
    long zsA, long zsB, long zsC) {
  constexpr int BN_ = 256;
  constexpr int BK = 64;                 // elements (128 bytes)
  constexpr int RA = BM_ / 128;          // stage loads per A-half per wave
  constexpr int HALF_A = (BM_ / 2) * 128;  // bytes
  constexpr int HALF_B = 128 * 128;
  constexpr int ATILE = BM_ * 128;
  constexpr int BTILE = BN_ * 128;
  constexpr int MREP = BM_ / 32;         // 8 or 4
  constexpr int MQ = MREP / 2;           // A frags per half (4 or 2)

  __shared__ alignas(16) char lds[(ATILE + BTILE) * 2];

  const int tid = threadIdx.x;
  const int l = tid & 63;
  const int w = tid >> 6;   // 0..7
  const int wm = w >> 2;    // 0..1
  const int wn = w & 3;     // 0..3

  // bijective XCD-chunked swizzle (nwg % 8 == 0 for all our grids)
  const int gx = gridDim.x;
  const int nwg = gridDim.x * gridDim.y;
  int n = blockIdx.y * gx + blockIdx.x;
  int n2 = (n & 7) * (nwg >> 3) + (n >> 3);
  const int tileM = (n2 / gx) * BM_;
  const int tileN = (n2 % gx) * BN_;

  const int z = blockIdx.z;
  const unsigned short* Ab = A + (size_t)z * zsA;
  const unsigned short* Bb = Bm + (size_t)z * zsB;

  // staging: per-lane pre-swizzled global col; linear LDS dest (wave-uniform base)
  const int srow = l >> 3;                       // 0..7 within 8-row wave chunk
  const int scol = (((l & 7) ^ srow) * 16);      // swizzled byte col within 128B row

  auto stageA = [&](int buf, int t, int h) {
#pragma unroll
    for (int r = 0; r < RA; ++r) {
      int row = h * (BM_ / 2) + r * 64 + w * 8 + srow;
      const char* g = (const char*)(Ab + (size_t)(tileM + row) * lda + t * BK) + scol;
      char* d = lds + buf * (ATILE + BTILE) + h * HALF_A + r * 8192 + w * 1024;
      __builtin_amdgcn_global_load_lds(
          (const __attribute__((address_space(1))) void*)g,
          (__attribute__((address_space(3))) void*)d, 16, 0, 0);
    }
  };
  auto stageB = [&](int buf, int t, int h) {
#pragma unroll
    for (int r = 0; r < 2; ++r) {
      int row = h * 128 + r * 64 + w * 8 + srow;
      const char* g = (const char*)(Bb + (size_t)(tileN + row) * ldb + t * BK) + scol;
      char* d = lds + buf * (ATILE + BTILE) + ATILE + h * HALF_B + r * 8192 + w * 1024;
      __builtin_amdgcn_global_load_lds(
          (const __attribute__((address_space(1))) void*)g,
          (__attribute__((address_space(3))) void*)d, 16, 0, 0);
    }
  };

  f32x4 acc[MREP][4];
#pragma unroll
  for (int m = 0; m < MREP; ++m)
#pragma unroll
    for (int nn = 0; nn < 4; ++nn) acc[m][nn] = f32x4{0.f, 0.f, 0.f, 0.f};

  // fragment ds_read (same XOR swizzle as staging)
  const int frow = l & 15;
  auto rdA = [&](int buf, int mh, int m, int kk) -> bf16x8 {
    int row = mh * (BM_ / 2) + wm * (BM_ / 4) + m * 16 + frow;
    int col = (kk * 64 + ((l >> 4) * 16)) ^ ((row & 7) << 4);
    return *reinterpret_cast<const bf16x8*>(lds + buf * (ATILE + BTILE) + row * 128 + col);
  };
  auto rdB = [&](int buf, int nh, int nn, int kk) -> bf16x8 {
    int row = nh * 128 + wn * 32 + nn * 16 + frow;
    int col = (kk * 64 + ((l >> 4) * 16)) ^ ((row & 7) << 4);
    return *reinterpret_cast<const bf16x8*>(lds + buf * (ATILE + BTILE) + ATILE + row * 128 + col);
  };

  bf16x8 avF[MQ][2];            // rotating A half set, full-K [m][kk]
  bf16x8 bv0[2][2], bv1[2][2];  // B halves, full-K [nn][kk], held per tile

  auto rdAfull = [&](int buf, int mh) {
#pragma unroll
    for (int m = 0; m < MQ; ++m)
#pragma unroll
      for (int kk = 0; kk < 2; ++kk) avF[m][kk] = rdA(buf, mh, m, kk);
  };
  auto rdBfull = [&](int buf, int nh, bf16x8 (&bv)[2][2]) {
#pragma unroll
    for (int nn = 0; nn < 2; ++nn)
#pragma unroll
      for (int kk = 0; kk < 2; ++kk) bv[nn][kk] = rdB(buf, nh, nn, kk);
  };
  // kk OUTER: per kk-step all MQ*2 accumulators independent (r14, proven)
  auto mfc = [&](int mh, bf16x8 (&bv)[2][2], int nh) {
    __builtin_amdgcn_s_setprio(1);
#pragma unroll
    for (int kk = 0; kk < 2; ++kk)
#pragma unroll
      for (int m = 0; m < MQ; ++m)
#pragma unroll
        for (int nn = 0; nn < 2; ++nn)
          acc[mh * MQ + m][nh * 2 + nn] = __builtin_amdgcn_mfma_f32_16x16x32_bf16(
              avF[m][kk], bv[nn][kk], acc[mh * MQ + m][nh * 2 + nn], 0, 0, 0);
    __builtin_amdgcn_s_setprio(0);
  };
  auto mfc2 = [&](int mh) {  // (A1,B1)+(A1,B0) merged, kk-outer
    __builtin_amdgcn_s_setprio(1);
#pragma unroll
    for (int kk = 0; kk < 2; ++kk)
#pragma unroll
      for (int m = 0; m < MQ; ++m) {
#pragma unroll
        for (int nn = 0; nn < 2; ++nn)
          acc[mh * MQ + m][2 + nn] = __builtin_amdgcn_mfma_f32_16x16x32_bf16(
              avF[m][kk], bv1[nn][kk], acc[mh * MQ + m][2 + nn], 0, 0, 0);
#pragma unroll
        for (int nn = 0; nn < 2; ++nn)
          acc[mh * MQ + m][nn] = __builtin_amdgcn_mfma_f32_16x16x32_bf16(
              avF[m][kk], bv0[nn][kk], acc[mh * MQ + m][nn], 0, 0, 0);
      }
    __builtin_amdgcn_s_setprio(0);
  };

  // prologue: stage tile 0 fully; single boundary wait
  stageA(0, 0, 0);
  stageB(0, 0, 0);
  stageB(0, 0, 1);
  stageA(0, 0, 1);
  waitvm<0>();
  BARRIER();

#pragma unroll 2
  for (int t = 0; t < NT - 1; ++t) {
    const int buf = t & 1, nb = buf ^ 1;
    // Whole tile body: NO intra-tile sync. Compiler pipelines reads/MFMAs;
    // stages for t+1 issue early and fly across the whole tile.
    rdAfull(buf, 0); rdBfull(buf, 0, bv0);
    stageA(nb, t + 1, 0); stageB(nb, t + 1, 0);
    mfc(0, bv0, 0);
    rdBfull(buf, 1, bv1);
    stageB(nb, t + 1, 1);
    mfc(0, bv1, 1);
    rdAfull(buf, 1);
    stageA(nb, t + 1, 1);
    mfc2(1);
    // tile boundary: drain own LDS reads (WAR), all t+1 loads resident (RAW)
    LGKM0();
    waitvm<0>();
    BARRIER();
  }
  {  // last tile: no staging, no boundary sync needed
    const int buf = (NT - 1) & 1;
    rdAfull(buf, 0); rdBfull(buf, 0, bv0);
    mfc(0, bv0, 0);
    rdBfull(buf, 1, bv1);
    mfc(0, bv1, 1);
    rdAfull(buf, 1);
    mfc2(1);
  }

  // epilogue: C/D layout (m89): col = lane&15, row = (lane>>4)*4 + j
  const int lr = (l >> 4) * 4;
  const int lc = l & 15;
#pragma unroll
  for (int mh = 0; mh < 2; ++mh) {
#pragma unroll
    for (int m = 0; m < MQ; ++m) {
#pragma unroll
      for (int nh = 0; nh < 2; ++nh) {
#pragma unroll
        for (int nn = 0; nn < 2; ++nn) {
          int gr = tileM + mh * (BM_ / 2) + wm * (BM_ / 4) + m * 16 + lr;
          int gc = tileN + nh * 128 + wn * 32 + nn * 16 + lc;
          f32x4 v = acc[mh * MQ + m][nh * 2 + nn];
          if constexpr (EP == 0 || EP == 3) {
            unsigned short* C = (unsigned short*)Cp + (size_t)z * zsC;
#pragma unroll
            for (int j = 0; j < 4; ++j) {
              float bb = (EP == 0) ? bias[gc] : bias[gr + j];
              C[(size_t)(gr + j) * ldc + gc] = f2bf(v[j] + bb);
            }
          } else {
            float* C = (float*)Cp + (size_t)z * zsC;
#pragma unroll
            for (int j = 0; j < 4; ++j)
              C[(size_t)(gr + j) * ldc + gc] = (EP == 1) ? v[j] * scale : v[j];
          }
        }
      }
    }
  }
}

// ---------------- row softmax: fp32 [8192 x 2048] -> bf16 P ----------------
__global__ __launch_bounds__(256) void softmax_kernel(const float* __restrict__ Sb,
                                                      unsigned short* __restrict__ P) {
  const size_t row = blockIdx.x;
  const float* sp = Sb + row * S_LEN;
  const int t = threadIdx.x;
  const int wid = t >> 6, lane = t & 63;
  float4 v0 = reinterpret_cast<const float4*>(sp)[t * 2];
  float4 v1 = reinterpret_cast<const float4*>(sp)[t * 2 + 1];
  float s[8] = {v0.x, v0.y, v0.z, v0.w, v1.x, v1.y, v1.z, v1.w};
  float mx = s[0];
#pragma unroll
  for (int i = 1; i < 8; ++i) mx = fmaxf(mx, s[i]);
#pragma unroll
  for (int o = 32; o > 0; o >>= 1) mx = fmaxf(mx, __shfl_xor(mx, o));
  __shared__ float redm[4];
  __shared__ float reds[4];
  if (lane == 0) redm[wid] = mx;
  __syncthreads();
  mx = fmaxf(fmaxf(redm[0], redm[1]), fmaxf(redm[2], redm[3]));
  float e[8];
  float sum = 0.f;
#pragma unroll
  for (int i = 0; i < 8; ++i) { e[i] = __expf(s[i] - mx); sum += e[i]; }
#pragma unroll
  for (int o = 32; o > 0; o >>= 1) sum += __shfl_xor(sum, o);
  if (lane == 0) reds[wid] = sum;
  __syncthreads();
  sum = reds[0] + reds[1] + reds[2] + reds[3];
  float inv = 1.0f / sum;
  ushort4 o0, o1;
  o0.x = f2bf(e[0] * inv); o0.y = f2bf(e[1] * inv); o0.z = f2bf(e[2] * inv); o0.w = f2bf(e[3] * inv);
  o1.x = f2bf(e[4] * inv); o1.y = f2bf(e[5] * inv); o1.z = f2bf(e[6] * inv); o1.w = f2bf(e[7] * inv);
  ushort4* dp = reinterpret_cast<ushort4*>(P + row * S_LEN);
  dp[t * 2] = o0;
  dp[t * 2 + 1] = o1;
}

extern "C" void kernel_launch(void* const* d_in, const int* in_sizes, int n_in,
                              void* d_out, int out_size, void* d_ws, size_t ws_size,
                              hipStream_t stream) {
  (void)in_sizes; (void)n_in; (void)out_size;
  const float* x = (const float*)d_in[0];
  const float* Wq = (const float*)d_in[1];
  const float* bq = (const float*)d_in[2];
  const float* Wk = (const float*)d_in[3];
  const float* bk = (const float*)d_in[4];
  const float* Wv = (const float*)d_in[5];
  const float* bv = (const float*)d_in[6];
  float* out = (float*)d_out;

  // workspace layout (bytes), total ~135 MB:
  //   xb   bf16 [8192][1024]    @ 0       (16 MB)
  //   Wqkb bf16 [2048][1024]    @ 16 MB   (4 MB)   -- [Wq;Wk]
  //   Wvb  bf16 [1024][1024]    @ 20 MB   (2 MB)
  //   bqk  f32  [2048]          @ 22 MB   (8 KB)
  //   QKb  bf16 [8192][2048]    @ 23 MB   (32 MB)  -- reused as P after scores
  //   Sb   f32  [4][2048][2048] @ 55 MB   (64 MB)
  //   Vt   bf16 [4][1024][2048] @ 119 MB  (16 MB)
  if (ws_size < 141557760ull) return;
  char* ws = (char*)d_ws;
  unsigned short* xb   = (unsigned short*)(ws);
  unsigned short* Wqkb = (unsigned short*)(ws + 16777216);
  unsigned short* Wvb  = (unsigned short*)(ws + 20971520);
  float*          bqk  = (float*)(ws + 23068672);
  unsigned short* QKb  = (unsigned short*)(ws + 24117248);
  float*          Sb   = (float*)(ws + 57671680);
  unsigned short* Vt   = (unsigned short*)(ws + 124780544);
  unsigned short* P    = QKb;  // alias: QKb dead after scores GEMM

  // 1) fused input+weight+bias prep (single launch)
  const int NX = MROWS * DMODEL / 4, NW = DMODEL * DMODEL / 4;
  prep_all_kernel<<<dim3((NX + 3 * NW) / 256), 256, 0, stream>>>(
      x, Wq, Wk, Wv, bq, bk, (ushort4*)xb, (ushort4*)Wqkb, (ushort4*)Wvb, (float4*)bqk);

  // 2) QK projection: [8192x2048] = x * [Wq;Wk]^T + bqk  (grid 256 = 1 round)
  gemm8<256, 0, 16><<<dim3(8, 32, 1), 512, 0, stream>>>(
      xb, Wqkb, QKb, bqk, 1024, 1024, 2048, 1.f, 0, 0, 0);

  // 3) Vt = Wv * x^T + bv (per batch): grid (8,8,4) = 256 half-size blocks
  gemm8<128, 3, 16><<<dim3(8, 8, 4), 512, 0, stream>>>(
      Wvb, xb, Vt, bv, 1024, 1024, 2048, 1.f,
      0, (long)S_LEN * DMODEL, (long)DMODEL * S_LEN);

  // 4) scores: Sb = Q * K^T * 0.125 (per batch M=N=2048, K=1024)
  gemm8<256, 1, 16><<<dim3(8, 8, 4), 512, 0, stream>>>(
      QKb, QKb + 1024, Sb, nullptr, 2048, 2048, 2048, 0.125f,
      (long)S_LEN * 2048, (long)S_LEN * 2048, (long)S_LEN * S_LEN);

  // 5) row softmax -> bf16 P (aliases QKb)
  softmax_kernel<<<dim3(MROWS), 256, 0, stream>>>(Sb, P);

  // 6) out = P * Vt^T (per batch M=2048, N=1024, K=2048; grid 256 = 1 round)
  gemm8<128, 2, 32><<<dim3(4, 16, 4), 512, 0, stream>>>(
      P, Vt, out, nullptr, 2048, 2048, 1024, 1.f,
      (long)S_LEN * S_LEN, (long)DMODEL * S_LEN, (long)S_LEN * DMODEL);
}